// Round 13
// baseline (59.038 us; speedup 1.0000x reference)
//
#include <hip/hip_runtime.h>
#include <math.h>

// B=4, X=128, T=256, HIDDEN=128, EMB=128, DH=32, LATENT=32, K=1024
// Outputs concat: u (131072), zt (1048576), px (524288)
//
// u[b,t,x] = K0 + mz*mp*( ft.M.fx + ft.a + bvec.fx + c0 )
//   M[j,i] = sum_k zt_Wo[j,k] wc_k px_Wo[i,k];  wc_k = wcd[k>>5]/32
//
// prep (129 blocks): block 0 -> wc,K0,a,bvec,c0; blocks 1..128 -> M tiles.
// main (512 blocks): 0-383 feat (R11 self-chained, validated); 384-511 u via M
//   (self-sufficient: own embedding chain + on-the-fly fx).

#define WS_WC  0
#define WS_K0  32
#define WS_C0  33
#define WS_A   64
#define WS_BV  192
#define WS_M   512

struct P {
    const float *x, *t, *param;
    const float *p2e_W1, *p2e_b1, *p2e_W2, *p2e_b2;
    const float *e2ex_W, *e2ex_b, *e2et_W, *e2et_b;
    const float *px_Wx, *px_bx, *px_We, *px_be, *px_Wo, *px_bo, *px_mult;
    const float *zt_Wx, *zt_bx, *zt_We, *zt_be, *zt_Wo, *zt_bo, *zt_mult;
    const float *h0, *blk_W1, *blk_b1, *blk_Wc, *blk_bc, *blk_W2, *blk_b2;
    const float *d_W, *d_b;
    float *out_u, *out_zt, *out_px, *ws;
};

__device__ __forceinline__ void fma4(float4& a, float s, const float4& v) {
    a.x += s * v.x; a.y += s * v.y; a.z += s * v.z; a.w += s * v.w;
}

// out[j] = bias[j] + sum_k vin[k] * W[k*128+j]; 256 threads. In-place safe.
__device__ __forceinline__ void gemv_stage(
    const float* __restrict__ W, const float* __restrict__ bias,
    const float* vin, float* vout, float* partf, int tid)
{
    const int j4 = tid & 31;
    const int sl = tid >> 5;
    float4 a4 = make_float4(0.f, 0.f, 0.f, 0.f);
    const float* Wp = W + sl * 16 * 128 + j4 * 4;
    #pragma unroll
    for (int k = 0; k < 16; ++k)
        fma4(a4, vin[sl * 16 + k], *(const float4*)&Wp[k * 128]);
    *(float4*)&partf[sl * 128 + j4 * 4] = a4;
    __syncthreads();
    if (tid < 128) {
        float v = bias[tid];
        #pragma unroll
        for (int q = 0; q < 8; ++q) v += partf[q * 128 + tid];
        vout[tid] = v;
    }
    __syncthreads();
}

// sw chain -> wcl[32]; optionally write ws wc + K0.
__device__ __forceinline__ void compute_wc(
    const P& p, float* sA, float* sB, float* partf, float* wcl,
    int tid, bool write_ws)
{
    if (tid < 128) sA[tid] = p.h0[tid];
    __syncthreads();
    gemv_stage(p.blk_W1, p.blk_b1, sA, sB, partf, tid);
    if (tid < 128) {
        float w2 = 0.f;
        const float4* rp = (const float4*)&p.blk_W2[tid * 128];
        #pragma unroll
        for (int m4 = 0; m4 < 32; ++m4) {
            const float4 wv = rp[m4];
            const float4 dv = *(const float4*)&p.d_W[m4 * 4];
            w2 += wv.x * dv.x + wv.y * dv.y + wv.z * dv.z + wv.w * dv.w;
        }
        const float sv = __sinf(sB[tid]) * w2;
        sA[tid] = sv;
        sB[tid] = (p.h0[tid] + p.blk_b2[tid]) * p.d_W[tid] + sv * p.blk_bc[tid];
    }
    __syncthreads();
    {
        const int d  = tid >> 3;
        const int sg = (tid & 7) * 16;
        float acc = 0.f;
        #pragma unroll
        for (int i4 = 0; i4 < 4; ++i4) {
            const float4 wv = *(const float4*)&p.blk_Wc[d * 128 + sg + i4 * 4];
            const float4 sv = *(const float4*)&sA[sg + i4 * 4];
            acc += wv.x * sv.x + wv.y * sv.y + wv.z * sv.z + wv.w * sv.w;
        }
        partf[d * 8 + (tid & 7)] = acc;
    }
    __syncthreads();
    if (tid < 32) {
        float w = 0.f;
        #pragma unroll
        for (int q = 0; q < 8; ++q) w += partf[tid * 8 + q];
        wcl[tid] = w * (1.0f / 32.0f);
        if (write_ws) p.ws[WS_WC + tid] = wcl[tid];
    }
    if (write_ws) {
        if (tid < 64) sB[tid] += sB[tid + 64];
        __syncthreads();
        if (tid == 0) {
            float K = p.d_b[0];
            #pragma unroll
            for (int i = 0; i < 64; ++i) K += sB[i];
            p.ws[WS_K0] = K;
        }
    }
    __syncthreads();
}

__global__ __launch_bounds__(256, 2) void prep_kernel(P p) {
    __shared__ float sA[128], sB[128];
    __shared__ float partf[1024];
    __shared__ float wcl[32];
    const int tid = threadIdx.x;
    const int bid = blockIdx.x;

    if (bid == 0) {
        __shared__ float wb[1024], zb[1024];
        compute_wc(p, sA, sB, partf, wcl, tid, true);
        {
            const int k4 = tid * 4;
            const float w = wcl[k4 >> 5];
            float4 bp = *(const float4*)&p.px_bo[k4];
            float4 bz = *(const float4*)&p.zt_bo[k4];
            float4 v1, v2;
            v1.x = w * bp.x; v1.y = w * bp.y; v1.z = w * bp.z; v1.w = w * bp.w;
            v2.x = w * bz.x; v2.y = w * bz.y; v2.z = w * bz.z; v2.w = w * bz.w;
            *(float4*)&wb[k4] = v1;
            *(float4*)&zb[k4] = v2;
            partf[tid] = v2.x * bp.x + v2.y * bp.y + v2.z * bp.z + v2.w * bp.w;
        }
        __syncthreads();
        if (tid < 128) {
            float acc = 0.f;
            const float4* rp = (const float4*)&p.zt_Wo[tid * 1024];
            #pragma unroll 8
            for (int k4 = 0; k4 < 256; ++k4) {
                const float4 wv = rp[k4];
                const float4 cv = *(const float4*)&wb[k4 * 4];
                acc += wv.x * cv.x + wv.y * cv.y + wv.z * cv.z + wv.w * cv.w;
            }
            p.ws[WS_A + tid] = acc;
        } else {
            const int i = tid - 128;
            float acc = 0.f;
            const float4* rp = (const float4*)&p.px_Wo[i * 1024];
            #pragma unroll 8
            for (int k4 = 0; k4 < 256; ++k4) {
                const float4 wv = rp[k4];
                const float4 cv = *(const float4*)&zb[k4 * 4];
                acc += wv.x * cv.x + wv.y * cv.y + wv.z * cv.z + wv.w * cv.w;
            }
            p.ws[WS_BV + i] = acc;
        }
        if (tid < 128) partf[tid] += partf[tid + 128];
        __syncthreads();
        if (tid < 64) partf[tid] += partf[tid + 64];
        __syncthreads();
        if (tid == 0) {
            float c = 0.f;
            #pragma unroll
            for (int i = 0; i < 64; ++i) c += partf[i];
            p.ws[WS_C0] = c;
        }
    } else {
        // M tile: 16 j x 8 i, k-split 2. mm in 0..127. (validated R12 code)
        compute_wc(p, sA, sB, partf, wcl, tid, false);
        const int mm = bid - 1;
        const int j0 = (mm >> 4) * 16;
        const int i0 = (mm & 15) * 8;
        const int o  = tid & 127;
        const int kh = tid >> 7;
        const int j  = j0 + (o >> 3);
        const int i  = i0 + (o & 7);
        float acc = 0.f;
        const float4* zp = (const float4*)&p.zt_Wo[j * 1024 + kh * 512];
        const float4* pp = (const float4*)&p.px_Wo[i * 1024 + kh * 512];
        #pragma unroll 8
        for (int k4 = 0; k4 < 128; ++k4) {
            const float4 zf = zp[k4];
            const float4 pf = pp[k4];
            const float w = wcl[(kh * 128 + k4) >> 3];
            acc += w * (zf.x * pf.x + zf.y * pf.y + zf.z * pf.z + zf.w * pf.w);
        }
        partf[kh * 128 + o] = acc;
        __syncthreads();
        if (tid < 128)
            p.ws[WS_M + j * 128 + i] = partf[tid] + partf[128 + tid];
    }
}

__global__ __launch_bounds__(256, 2) void main_kernel(P p) {
    __shared__ float vin[128], vout[128];
    __shared__ float partf[1024];
    __shared__ float f[8 * 128];
    const int tid = threadIdx.x;
    const int bid = blockIdx.x;

    if (bid < 384) {
        // ============ feat (R11 validated, self-chained) ============
        const bool is_zt = bid >= 128;
        const int un = is_zt ? bid - 128 : bid;
        const int rt = un >> 1, cs = un & 1;
        const int r0 = rt * 8;
        const int b = is_zt ? (r0 >> 8) : (r0 >> 7);

        const float* Wh = is_zt ? p.e2et_W : p.e2ex_W;
        const float* bh = is_zt ? p.e2et_b : p.e2ex_b;
        const float* We = is_zt ? p.zt_We : p.px_We;
        const float* be = is_zt ? p.zt_be : p.px_be;
        const float* Wx = is_zt ? p.zt_Wx : p.px_Wx;
        const float* bxv = is_zt ? p.zt_bx : p.px_bx;
        const float* Wo = is_zt ? p.zt_Wo : p.px_Wo;
        const float* bo = is_zt ? p.zt_bo : p.px_bo;
        const float* coord = is_zt ? p.t : p.x;
        const float mult = is_zt ? p.zt_mult[0] : p.px_mult[0];
        float* outp = is_zt ? p.out_zt : p.out_px;

        if (tid < 128) {
            float a = p.p2e_b1[tid];
            #pragma unroll
            for (int q = 0; q < 16; ++q)
                a += p.param[b * 16 + q] * p.p2e_W1[q * 128 + tid];
            vin[tid] = __sinf(a);
        }
        __syncthreads();
        gemv_stage(p.p2e_W2, p.p2e_b2, vin, vout, partf, tid);   // e
        gemv_stage(Wh, bh, vout, vin, partf, tid);               // ex/et
        gemv_stage(We, be, vin, vout, partf, tid);               // g
        if (tid < 128) {
            const float g = vout[tid];
            const float wxj = Wx[tid], bxj = bxv[tid];
            #pragma unroll
            for (int rr = 0; rr < 8; ++rr)
                f[rr * 128 + tid] = __sinf(coord[r0 + rr] * wxj + bxj) * g;
        }
        __syncthreads();

        const int c = tid & 127;
        const int h = tid >> 7;
        const int c0 = cs * 512 + c * 4;
        const float* wp = Wo + c0;
        const float* fr = f + h * 4 * 128;

        float4 acc[4];
        #pragma unroll
        for (int rr = 0; rr < 4; ++rr) acc[rr] = make_float4(0.f, 0.f, 0.f, 0.f);

        float4 wA[8], wB[8];
        #pragma unroll
        for (int i = 0; i < 8; ++i) wA[i] = *(const float4*)&wp[i * 1024];

        #pragma unroll
        for (int g2 = 0; g2 < 8; ++g2) {
            #pragma unroll
            for (int i = 0; i < 8; ++i)
                wB[i] = *(const float4*)&wp[((2 * g2 + 1) * 8 + i) * 1024];
            {
                const int k0 = 16 * g2;
                #pragma unroll
                for (int rr = 0; rr < 4; ++rr) {
                    const float4 f0 = *(const float4*)&fr[rr * 128 + k0];
                    const float4 f1 = *(const float4*)&fr[rr * 128 + k0 + 4];
                    fma4(acc[rr], f0.x, wA[0]); fma4(acc[rr], f0.y, wA[1]);
                    fma4(acc[rr], f0.z, wA[2]); fma4(acc[rr], f0.w, wA[3]);
                    fma4(acc[rr], f1.x, wA[4]); fma4(acc[rr], f1.y, wA[5]);
                    fma4(acc[rr], f1.z, wA[6]); fma4(acc[rr], f1.w, wA[7]);
                }
            }
            if (g2 < 7) {
                #pragma unroll
                for (int i = 0; i < 8; ++i)
                    wA[i] = *(const float4*)&wp[((2 * g2 + 2) * 8 + i) * 1024];
            }
            {
                const int k0 = 16 * g2 + 8;
                #pragma unroll
                for (int rr = 0; rr < 4; ++rr) {
                    const float4 f0 = *(const float4*)&fr[rr * 128 + k0];
                    const float4 f1 = *(const float4*)&fr[rr * 128 + k0 + 4];
                    fma4(acc[rr], f0.x, wB[0]); fma4(acc[rr], f0.y, wB[1]);
                    fma4(acc[rr], f0.z, wB[2]); fma4(acc[rr], f0.w, wB[3]);
                    fma4(acc[rr], f1.x, wB[4]); fma4(acc[rr], f1.y, wB[5]);
                    fma4(acc[rr], f1.z, wB[6]); fma4(acc[rr], f1.w, wB[7]);
                }
            }
        }

        const float4 bias = *(const float4*)&bo[c0];
        #pragma unroll
        for (int rr = 0; rr < 4; ++rr) {
            float4 v;
            v.x = mult * (acc[rr].x + bias.x);
            v.y = mult * (acc[rr].y + bias.y);
            v.z = mult * (acc[rr].z + bias.z);
            v.w = mult * (acc[rr].w + bias.w);
            *(float4*)&outp[(r0 + h * 4 + rr) * 1024 + c0] = v;
        }
    } else {
        // ============ u via M (self-sufficient) ============
        __shared__ float wl[8][132];
        __shared__ float gxl[128], gtl[128];
        __shared__ float wxb[128], bxb[128];
        __shared__ float atl[8];
        const int m = bid - 384;           // 0..127
        const int b = m >> 5;
        const int t0 = (m & 31) * 8;

        // own embedding chain: e -> (ex, et) -> (gx, gt)
        if (tid < 128) {
            float a = p.p2e_b1[tid];
            #pragma unroll
            for (int q = 0; q < 16; ++q)
                a += p.param[b * 16 + q] * p.p2e_W1[q * 128 + tid];
            vin[tid] = __sinf(a);
            wxb[tid] = p.px_Wx[tid]; bxb[tid] = p.px_bx[tid];
        }
        __syncthreads();
        gemv_stage(p.p2e_W2, p.p2e_b2, vin, vout, partf, tid);   // e in vout
        gemv_stage(p.e2ex_W, p.e2ex_b, vout, gxl, partf, tid);   // ex in gxl
        gemv_stage(p.e2et_W, p.e2et_b, vout, vin, partf, tid);   // et in vin
        gemv_stage(p.px_We,  p.px_be,  gxl, gxl, partf, tid);    // gx (in-place)
        gemv_stage(p.zt_We,  p.zt_be,  vin, gtl, partf, tid);    // gt

        // ft rows (8 x 128)
        {
            const int r = tid >> 5;
            const int j0 = (tid & 31) * 4;
            const float tc = p.t[b * 256 + t0 + r];
            #pragma unroll
            for (int q = 0; q < 4; ++q) {
                const int j = j0 + q;
                f[r * 128 + j] = __sinf(tc * p.zt_Wx[j] + p.zt_bx[j]) * gtl[j];
            }
        }
        __syncthreads();

        // W[r][jo] = bvec[jo] + sum_ji f[r][ji] * M[ji*128+jo]
        {
            const int r   = tid >> 5;
            const int jo4 = (tid & 31) * 4;
            float4 acc = make_float4(0.f, 0.f, 0.f, 0.f);
            const float* frow = f + r * 128;
            const float* Mb = p.ws + WS_M;
            #pragma unroll 8
            for (int ji = 0; ji < 128; ++ji)
                fma4(acc, frow[ji], *(const float4*)&Mb[ji * 128 + jo4]);
            const float4 bv = *(const float4*)&p.ws[WS_BV + jo4];
            acc.x += bv.x; acc.y += bv.y; acc.z += bv.z; acc.w += bv.w;
            *(float4*)&wl[r][jo4] = acc;
        }
        if (tid < 8) {
            const float* frow = f + tid * 128;
            float s = p.ws[WS_C0];
            #pragma unroll 8
            for (int j4 = 0; j4 < 32; ++j4) {
                const float4 av = *(const float4*)&p.ws[WS_A + j4 * 4];
                const float4 fv = *(const float4*)&frow[j4 * 4];
                s += av.x * fv.x + av.y * fv.y + av.z * fv.z + av.w * fv.w;
            }
            atl[tid] = s;
        }
        __syncthreads();

        // U[r][x]: thread x = tid&127, rows rh*4..rh*4+3 (rh = tid>>7)
        {
            const int xx = tid & 127;
            const int rh = tid >> 7;
            const float xc = p.x[b * 128 + xx];
            float a0 = 0.f, a1 = 0.f, a2 = 0.f, a3 = 0.f;
            #pragma unroll 4
            for (int j4 = 0; j4 < 32; ++j4) {
                float4 fx4;
                {
                    const int j = j4 * 4;
                    fx4.x = __sinf(xc * wxb[j]     + bxb[j])     * gxl[j];
                    fx4.y = __sinf(xc * wxb[j + 1] + bxb[j + 1]) * gxl[j + 1];
                    fx4.z = __sinf(xc * wxb[j + 2] + bxb[j + 2]) * gxl[j + 2];
                    fx4.w = __sinf(xc * wxb[j + 3] + bxb[j + 3]) * gxl[j + 3];
                }
                const float4 w0 = *(const float4*)&wl[rh * 4][j4 * 4];
                const float4 w1 = *(const float4*)&wl[rh * 4 + 1][j4 * 4];
                const float4 w2 = *(const float4*)&wl[rh * 4 + 2][j4 * 4];
                const float4 w3 = *(const float4*)&wl[rh * 4 + 3][j4 * 4];
                a0 += w0.x * fx4.x + w0.y * fx4.y + w0.z * fx4.z + w0.w * fx4.w;
                a1 += w1.x * fx4.x + w1.y * fx4.y + w1.z * fx4.z + w1.w * fx4.w;
                a2 += w2.x * fx4.x + w2.y * fx4.y + w2.z * fx4.z + w2.w * fx4.w;
                a3 += w3.x * fx4.x + w3.y * fx4.y + w3.z * fx4.z + w3.w * fx4.w;
            }
            const float mzmp = p.zt_mult[0] * p.px_mult[0];
            const float K0 = p.ws[WS_K0];
            float* uo = p.out_u + (b * 256 + t0 + rh * 4) * 128 + xx;
            uo[0]       = K0 + mzmp * (atl[rh * 4]     + a0);
            uo[128]     = K0 + mzmp * (atl[rh * 4 + 1] + a1);
            uo[256]     = K0 + mzmp * (atl[rh * 4 + 2] + a2);
            uo[384]     = K0 + mzmp * (atl[rh * 4 + 3] + a3);
        }
    }
}

extern "C" void kernel_launch(void* const* d_in, const int* in_sizes, int n_in,
                              void* d_out, int out_size, void* d_ws, size_t ws_size,
                              hipStream_t stream) {
    float* out = (float*)d_out;

    P prm;
    prm.x       = (const float*)d_in[0];
    prm.t       = (const float*)d_in[1];
    prm.param   = (const float*)d_in[2];
    prm.p2e_W1  = (const float*)d_in[3];
    prm.p2e_b1  = (const float*)d_in[4];
    prm.p2e_W2  = (const float*)d_in[5];
    prm.p2e_b2  = (const float*)d_in[6];
    prm.e2ex_W  = (const float*)d_in[7];
    prm.e2ex_b  = (const float*)d_in[8];
    prm.e2et_W  = (const float*)d_in[9];
    prm.e2et_b  = (const float*)d_in[10];
    prm.px_Wx   = (const float*)d_in[11];
    prm.px_bx   = (const float*)d_in[12];
    prm.px_We   = (const float*)d_in[13];
    prm.px_be   = (const float*)d_in[14];
    prm.px_Wo   = (const float*)d_in[15];
    prm.px_bo   = (const float*)d_in[16];
    prm.px_mult = (const float*)d_in[17];
    prm.zt_Wx   = (const float*)d_in[18];
    prm.zt_bx   = (const float*)d_in[19];
    prm.zt_We   = (const float*)d_in[20];
    prm.zt_be   = (const float*)d_in[21];
    prm.zt_Wo   = (const float*)d_in[22];
    prm.zt_bo   = (const float*)d_in[23];
    prm.zt_mult = (const float*)d_in[24];
    prm.h0      = (const float*)d_in[25];
    prm.blk_W1  = (const float*)d_in[26];
    prm.blk_b1  = (const float*)d_in[27];
    prm.blk_Wc  = (const float*)d_in[28];
    prm.blk_bc  = (const float*)d_in[29];
    prm.blk_W2  = (const float*)d_in[30];
    prm.blk_b2  = (const float*)d_in[31];
    prm.d_W     = (const float*)d_in[32];
    prm.d_b     = (const float*)d_in[33];
    prm.out_u   = out;                        // 131072
    prm.out_zt  = out + 131072;               // 1048576
    prm.out_px  = out + 131072 + 1048576;     // 524288
    prm.ws      = (float*)d_ws;

    prep_kernel<<<129, 256, 0, stream>>>(prm);
    main_kernel<<<512, 256, 0, stream>>>(prm);
}

// Round 14
// 50.137 us; speedup vs baseline: 1.1775x; 1.1775x over previous
//
#include <hip/hip_runtime.h>
#include <math.h>

// B=4, X=128, T=256, HIDDEN=128, EMB=128, DH=32, LATENT=32, K=1024
// Outputs concat: u (131072), zt (1048576), px (524288)
// u[b,t,x] = K0 + sum_k zt[b,t,k]*px[b,x,k]*wc[k>>5]   (wc = wcd/32)
//
// R14 = R11 structure with 512-thread blocks in both kernels (2x waves/SIMD,
// same grids, same traffic, same 2 launches).
//   feat_kernel: 385 blocks x 512 thr. bid<384 feat unit; bid==384 wc/K0.
//   u_kernel: 512 blocks x 512 thr, K split in-block (kh), LDS pair-reduce.

struct P {
    const float *x, *t, *param;
    const float *p2e_W1, *p2e_b1, *p2e_W2, *p2e_b2;
    const float *e2ex_W, *e2ex_b, *e2et_W, *e2et_b;
    const float *px_Wx, *px_bx, *px_We, *px_be, *px_Wo, *px_bo, *px_mult;
    const float *zt_Wx, *zt_bx, *zt_We, *zt_be, *zt_Wo, *zt_bo, *zt_mult;
    const float *h0, *blk_W1, *blk_b1, *blk_Wc, *blk_bc, *blk_W2, *blk_b2;
    const float *d_W, *d_b;
    float *out_u, *out_zt, *out_px, *ws;
};

__device__ __forceinline__ void fma4(float4& a, float s, const float4& v) {
    a.x += s * v.x; a.y += s * v.y; a.z += s * v.z; a.w += s * v.w;
}

// out[j] = bias[j] + sum_k vin[k] * W[k*128+j]; 512 threads, 16 k-slices of 8.
__device__ __forceinline__ void gemv_stage512(
    const float* __restrict__ W, const float* __restrict__ bias,
    const float* vin, float* vout, float* partf, int tid)
{
    const int j4 = tid & 31;
    const int sl = tid >> 5;              // 0..15
    float4 a4 = make_float4(0.f, 0.f, 0.f, 0.f);
    const float* Wp = W + sl * 8 * 128 + j4 * 4;
    #pragma unroll
    for (int k = 0; k < 8; ++k)
        fma4(a4, vin[sl * 8 + k], *(const float4*)&Wp[k * 128]);
    *(float4*)&partf[sl * 128 + j4 * 4] = a4;
    __syncthreads();
    if (tid < 128) {
        float v = bias[tid];
        #pragma unroll
        for (int q = 0; q < 16; ++q) v += partf[q * 128 + tid];
        vout[tid] = v;
    }
    __syncthreads();
}

__global__ __launch_bounds__(512) void feat_kernel(P p) {
    __shared__ float vin[128], vout[128];
    __shared__ float partf[2048];
    __shared__ float f[8 * 128];
    const int tid = threadIdx.x;
    const int bid = blockIdx.x;

    if (bid < 384) {
        const bool is_zt = bid >= 128;
        const int un = is_zt ? bid - 128 : bid;
        const int rt = un >> 1, cs = un & 1;
        const int r0 = rt * 8;
        const int b = is_zt ? (r0 >> 8) : (r0 >> 7);

        const float* Wh = is_zt ? p.e2et_W : p.e2ex_W;
        const float* bh = is_zt ? p.e2et_b : p.e2ex_b;
        const float* We = is_zt ? p.zt_We : p.px_We;
        const float* be = is_zt ? p.zt_be : p.px_be;
        const float* Wx = is_zt ? p.zt_Wx : p.px_Wx;
        const float* bxv = is_zt ? p.zt_bx : p.px_bx;
        const float* Wo = is_zt ? p.zt_Wo : p.px_Wo;
        const float* bo = is_zt ? p.zt_bo : p.px_bo;
        const float* coord = is_zt ? p.t : p.x;
        const float mult = is_zt ? p.zt_mult[0] : p.px_mult[0];
        float* outp = is_zt ? p.out_zt : p.out_px;

        // ---- g-chain (512-thread sliced GEMVs) ----
        if (tid < 128) {
            float a = p.p2e_b1[tid];
            #pragma unroll
            for (int q = 0; q < 16; ++q)
                a += p.param[b * 16 + q] * p.p2e_W1[q * 128 + tid];
            vin[tid] = __sinf(a);
        }
        __syncthreads();
        gemv_stage512(p.p2e_W2, p.p2e_b2, vin, vout, partf, tid);  // e
        gemv_stage512(Wh, bh, vout, vin, partf, tid);              // ex/et
        gemv_stage512(We, be, vin, vout, partf, tid);              // g
        if (tid < 128) {
            const float g = vout[tid];
            const float wxj = Wx[tid], bxj = bxv[tid];
            #pragma unroll
            for (int rr = 0; rr < 8; ++rr)
                f[rr * 128 + tid] = __sinf(coord[r0 + rr] * wxj + bxj) * g;
        }
        __syncthreads();

        // ---- GEMM 8 rows x 512 cols; thread (c=tid&127, h=tid>>7): 2 rows ----
        const int c = tid & 127;
        const int h = tid >> 7;            // 0..3
        const int c0 = cs * 512 + c * 4;
        const float* wp = Wo + c0;
        const float* fr = f + h * 2 * 128;

        float4 acc[2];
        acc[0] = make_float4(0.f, 0.f, 0.f, 0.f);
        acc[1] = make_float4(0.f, 0.f, 0.f, 0.f);

        float4 wA[8], wB[8];
        #pragma unroll
        for (int i = 0; i < 8; ++i) wA[i] = *(const float4*)&wp[i * 1024];

        #pragma unroll
        for (int g2 = 0; g2 < 8; ++g2) {
            #pragma unroll
            for (int i = 0; i < 8; ++i)
                wB[i] = *(const float4*)&wp[((2 * g2 + 1) * 8 + i) * 1024];
            {
                const int k0 = 16 * g2;
                #pragma unroll
                for (int rr = 0; rr < 2; ++rr) {
                    const float4 f0 = *(const float4*)&fr[rr * 128 + k0];
                    const float4 f1 = *(const float4*)&fr[rr * 128 + k0 + 4];
                    fma4(acc[rr], f0.x, wA[0]); fma4(acc[rr], f0.y, wA[1]);
                    fma4(acc[rr], f0.z, wA[2]); fma4(acc[rr], f0.w, wA[3]);
                    fma4(acc[rr], f1.x, wA[4]); fma4(acc[rr], f1.y, wA[5]);
                    fma4(acc[rr], f1.z, wA[6]); fma4(acc[rr], f1.w, wA[7]);
                }
            }
            if (g2 < 7) {
                #pragma unroll
                for (int i = 0; i < 8; ++i)
                    wA[i] = *(const float4*)&wp[((2 * g2 + 2) * 8 + i) * 1024];
            }
            {
                const int k0 = 16 * g2 + 8;
                #pragma unroll
                for (int rr = 0; rr < 2; ++rr) {
                    const float4 f0 = *(const float4*)&fr[rr * 128 + k0];
                    const float4 f1 = *(const float4*)&fr[rr * 128 + k0 + 4];
                    fma4(acc[rr], f0.x, wB[0]); fma4(acc[rr], f0.y, wB[1]);
                    fma4(acc[rr], f0.z, wB[2]); fma4(acc[rr], f0.w, wB[3]);
                    fma4(acc[rr], f1.x, wB[4]); fma4(acc[rr], f1.y, wB[5]);
                    fma4(acc[rr], f1.z, wB[6]); fma4(acc[rr], f1.w, wB[7]);
                }
            }
        }

        const float4 bias = *(const float4*)&bo[c0];
        #pragma unroll
        for (int rr = 0; rr < 2; ++rr) {
            float4 v;
            v.x = mult * (acc[rr].x + bias.x);
            v.y = mult * (acc[rr].y + bias.y);
            v.z = mult * (acc[rr].z + bias.z);
            v.w = mult * (acc[rr].w + bias.w);
            *(float4*)&outp[(r0 + h * 2 + rr) * 1024 + c0] = v;
        }
    } else {
        // ================= constants -> ws[0..31]=wc, ws[32]=K0 =============
        __shared__ float dws[128];
        if (tid < 128) { vin[tid] = p.h0[tid]; dws[tid] = p.d_W[tid]; }
        __syncthreads();
        gemv_stage512(p.blk_W1, p.blk_b1, vin, vout, partf, tid);   // sacc
        if (tid < 128) {
            float w2 = 0.f;
            const float4* rp = (const float4*)&p.blk_W2[tid * 128];
            #pragma unroll
            for (int m4 = 0; m4 < 32; ++m4) {
                const float4 wv = rp[m4];
                const float4 dv = *(const float4*)&dws[m4 * 4];
                w2 += wv.x * dv.x + wv.y * dv.y + wv.z * dv.z + wv.w * dv.w;
            }
            const float sv = __sinf(vout[tid]) * w2;
            vin[tid] = sv;                                    // sw
            vout[tid] = (p.h0[tid] + p.blk_b2[tid]) * dws[tid] + sv * p.blk_bc[tid];
        }
        __syncthreads();
        if (tid < 256) {
            const int d  = tid >> 3;
            const int sg = (tid & 7) * 16;
            float acc = 0.f;
            #pragma unroll
            for (int i4 = 0; i4 < 4; ++i4) {
                const float4 wv = *(const float4*)&p.blk_Wc[d * 128 + sg + i4 * 4];
                const float4 sv = *(const float4*)&vin[sg + i4 * 4];
                acc += wv.x * sv.x + wv.y * sv.y + wv.z * sv.z + wv.w * sv.w;
            }
            partf[d * 8 + (tid & 7)] = acc;
        }
        __syncthreads();
        if (tid < 32) {
            float w = 0.f;
            #pragma unroll
            for (int q = 0; q < 8; ++q) w += partf[tid * 8 + q];
            p.ws[tid] = w * (1.0f / 32.0f);
        }
        if (tid < 64) vout[tid] += vout[tid + 64];
        __syncthreads();
        if (tid == 0) {
            float K = p.d_b[0];
            #pragma unroll
            for (int i = 0; i < 64; ++i) K += vout[i];
            p.ws[32] = K;
        }
    }
}

// u: 512 blocks x 512 thr. Block = (b, 8 t-rows, 32 x). In-block k-split:
// kh = tid>>8 handles k-half of each 256-k chunk. LDS pair-reduce at end.
__global__ __launch_bounds__(512) void u_kernel(
    const float* __restrict__ zt, const float* __restrict__ px,
    const float* __restrict__ ws, float* __restrict__ out_u)
{
    __shared__ float4 pxs4[2080];      // [32][65]
    __shared__ float wcs[32];
    __shared__ float pred[8][33];      // kh=1 partials
    const int tid = threadIdx.x;
    const int bid = blockIdx.x;
    const int b   = bid >> 7;
    const int rem = bid & 127;
    const int t0  = (rem >> 2) * 8;
    const int x0  = (rem & 3) * 32;

    if (tid < 32) wcs[tid] = ws[tid];
    const float K0 = ws[32];
    const int tx = tid & 31;
    const int ty = (tid >> 5) & 7;     // 0..7
    const int kh = tid >> 8;           // 0..1
    const float* ztb = zt + (b * 256 + t0) * 1024;
    const float* pxb = px + (b * 128 + x0) * 1024;
    __syncthreads();

    float acc = 0.f;
    for (int chunk = 0; chunk < 4; ++chunk) {
        const int kc = chunk * 256;
        if (chunk) __syncthreads();
        // stage px chunk: 32 rows x 64 f4, scaled; 4 f4 per thread
        #pragma unroll
        for (int i = 0; i < 4; ++i) {
            const int m  = tid + 512 * i;
            const int xx = m >> 6;
            const int jf = m & 63;
            float4 v = *(const float4*)&pxb[xx * 1024 + kc + jf * 4];
            const float sc = wcs[(kc >> 5) + (jf >> 3)];
            v.x *= sc; v.y *= sc; v.z *= sc; v.w *= sc;
            pxs4[xx * 65 + jf] = v;
        }
        __syncthreads();

        const int kb = kc + kh * 128;          // this thread's k-base
        float4 za[8];
        #pragma unroll
        for (int j2 = 0; j2 < 8; ++j2)
            za[j2] = *(const float4*)&ztb[ty * 1024 + kb + j2 * 4];
        #pragma unroll
        for (int jj = 0; jj < 4; ++jj) {
            float4 nz[8];
            if (jj < 3) {
                const int koff = kb + (jj + 1) * 32;
                #pragma unroll
                for (int j2 = 0; j2 < 8; ++j2)
                    nz[j2] = *(const float4*)&ztb[ty * 1024 + koff + j2 * 4];
            }
            #pragma unroll
            for (int j2 = 0; j2 < 8; ++j2) {
                const float4 q = pxs4[tx * 65 + kh * 32 + jj * 8 + j2];
                acc += za[j2].x * q.x + za[j2].y * q.y
                     + za[j2].z * q.z + za[j2].w * q.w;
            }
            if (jj < 3) {
                #pragma unroll
                for (int j2 = 0; j2 < 8; ++j2) za[j2] = nz[j2];
            }
        }
    }

    __syncthreads();
    if (kh == 1) pred[ty][tx] = acc;
    __syncthreads();
    if (kh == 0)
        out_u[(b * 256 + t0 + ty) * 128 + x0 + tx] = K0 + acc + pred[ty][tx];
}

extern "C" void kernel_launch(void* const* d_in, const int* in_sizes, int n_in,
                              void* d_out, int out_size, void* d_ws, size_t ws_size,
                              hipStream_t stream) {
    float* out = (float*)d_out;
    float* ws  = (float*)d_ws;

    P prm;
    prm.x       = (const float*)d_in[0];
    prm.t       = (const float*)d_in[1];
    prm.param   = (const float*)d_in[2];
    prm.p2e_W1  = (const float*)d_in[3];
    prm.p2e_b1  = (const float*)d_in[4];
    prm.p2e_W2  = (const float*)d_in[5];
    prm.p2e_b2  = (const float*)d_in[6];
    prm.e2ex_W  = (const float*)d_in[7];
    prm.e2ex_b  = (const float*)d_in[8];
    prm.e2et_W  = (const float*)d_in[9];
    prm.e2et_b  = (const float*)d_in[10];
    prm.px_Wx   = (const float*)d_in[11];
    prm.px_bx   = (const float*)d_in[12];
    prm.px_We   = (const float*)d_in[13];
    prm.px_be   = (const float*)d_in[14];
    prm.px_Wo   = (const float*)d_in[15];
    prm.px_bo   = (const float*)d_in[16];
    prm.px_mult = (const float*)d_in[17];
    prm.zt_Wx   = (const float*)d_in[18];
    prm.zt_bx   = (const float*)d_in[19];
    prm.zt_We   = (const float*)d_in[20];
    prm.zt_be   = (const float*)d_in[21];
    prm.zt_Wo   = (const float*)d_in[22];
    prm.zt_bo   = (const float*)d_in[23];
    prm.zt_mult = (const float*)d_in[24];
    prm.h0      = (const float*)d_in[25];
    prm.blk_W1  = (const float*)d_in[26];
    prm.blk_b1  = (const float*)d_in[27];
    prm.blk_Wc  = (const float*)d_in[28];
    prm.blk_bc  = (const float*)d_in[29];
    prm.blk_W2  = (const float*)d_in[30];
    prm.blk_b2  = (const float*)d_in[31];
    prm.d_W     = (const float*)d_in[32];
    prm.d_b     = (const float*)d_in[33];
    prm.out_u   = out;                        // 131072
    prm.out_zt  = out + 131072;               // 1048576
    prm.out_px  = out + 131072 + 1048576;     // 524288
    prm.ws      = ws;

    feat_kernel<<<385, 512, 0, stream>>>(prm);
    u_kernel<<<512, 512, 0, stream>>>(prm.out_zt, prm.out_px, ws, out);
}

// Round 15
// 46.697 us; speedup vs baseline: 1.2643x; 1.0737x over previous
//
#include <hip/hip_runtime.h>
#include <math.h>

// B=4, X=128, T=256, HIDDEN=128, EMB=128, DH=32, LATENT=32, K=1024
// Outputs concat: u (131072), zt (1048576), px (524288)
// u[b,t,x] = K0 + sum_k zt[b,t,k]*px[b,x,k]*wc[k>>5]   (wc = wcd/32)
//
// R15 = R11 with feat GEMM re-tiled: 32 rows x 128 cols per block, weights
// staged through LDS once (24 MB total vs R11's 196 MB), ft transposed in LDS.
// u_kernel and constants block are R11 verbatim.

struct P {
    const float *x, *t, *param;
    const float *p2e_W1, *p2e_b1, *p2e_W2, *p2e_b2;
    const float *e2ex_W, *e2ex_b, *e2et_W, *e2et_b;
    const float *px_Wx, *px_bx, *px_We, *px_be, *px_Wo, *px_bo, *px_mult;
    const float *zt_Wx, *zt_bx, *zt_We, *zt_be, *zt_Wo, *zt_bo, *zt_mult;
    const float *h0, *blk_W1, *blk_b1, *blk_Wc, *blk_bc, *blk_W2, *blk_b2;
    const float *d_W, *d_b;
    float *out_u, *out_zt, *out_px, *ws;
};

__device__ __forceinline__ void fma4(float4& a, float s, const float4& v) {
    a.x += s * v.x; a.y += s * v.y; a.z += s * v.z; a.w += s * v.w;
}

// out[j] = bias[j] + sum_k vin[k] * W[k*128+j]; 256 threads. (R11 validated)
__device__ __forceinline__ void gemv_stage(
    const float* __restrict__ W, const float* __restrict__ bias,
    const float* vin, float* vout, float* partf, int tid)
{
    const int j4 = tid & 31;
    const int sl = tid >> 5;
    float4 a4 = make_float4(0.f, 0.f, 0.f, 0.f);
    const float* Wp = W + sl * 16 * 128 + j4 * 4;
    #pragma unroll
    for (int k = 0; k < 16; ++k)
        fma4(a4, vin[sl * 16 + k], *(const float4*)&Wp[k * 128]);
    *(float4*)&partf[sl * 128 + j4 * 4] = a4;
    __syncthreads();
    if (tid < 128) {
        float v = bias[tid];
        #pragma unroll
        for (int q = 0; q < 8; ++q) v += partf[q * 128 + tid];
        vout[tid] = v;
    }
    __syncthreads();
}

__global__ __launch_bounds__(256, 2) void feat_kernel(P p) {
    __shared__ float vin[128], vout[128];
    __shared__ float partf[1024];
    __shared__ float ft[128 * 36];      // f^T [k][row], row-pad 36 (f4-aligned)
    __shared__ float wlds[32 * 128];    // weight chunk [k][col]
    const int tid = threadIdx.x;
    const int bid = blockIdx.x;

    if (bid < 384) {
        // decode: px blocks 0-127 (4b x 4rt x 8cq), zt blocks 128-383 (4b x 8rt x 8cq)
        const bool is_zt = bid >= 128;
        int b, rt, cq8;
        if (!is_zt) { const int un = bid;       b = un >> 5; rt = (un >> 3) & 3; cq8 = un & 7; }
        else        { const int un = bid - 128; b = un >> 6; rt = (un >> 3) & 7; cq8 = un & 7; }
        const int r0  = b * (is_zt ? 256 : 128) + rt * 32;   // global row
        const int co0 = cq8 * 128;

        const float* Wh = is_zt ? p.e2et_W : p.e2ex_W;
        const float* bh = is_zt ? p.e2et_b : p.e2ex_b;
        const float* We = is_zt ? p.zt_We : p.px_We;
        const float* be = is_zt ? p.zt_be : p.px_be;
        const float* Wx = is_zt ? p.zt_Wx : p.px_Wx;
        const float* bxv = is_zt ? p.zt_bx : p.px_bx;
        const float* Wo = is_zt ? p.zt_Wo : p.px_Wo;
        const float* bo = is_zt ? p.zt_bo : p.px_bo;
        const float* coord = is_zt ? p.t : p.x;
        const float mult = is_zt ? p.zt_mult[0] : p.px_mult[0];
        float* outp = is_zt ? p.out_zt : p.out_px;

        // ---- g-chain (R11 validated) ----
        if (tid < 128) {
            float a = p.p2e_b1[tid];
            #pragma unroll
            for (int q = 0; q < 16; ++q)
                a += p.param[b * 16 + q] * p.p2e_W1[q * 128 + tid];
            vin[tid] = __sinf(a);
        }
        __syncthreads();
        gemv_stage(p.p2e_W2, p.p2e_b2, vin, vout, partf, tid);   // e
        gemv_stage(Wh, bh, vout, vin, partf, tid);               // ex/et
        gemv_stage(We, be, vin, vout, partf, tid);               // g in vout

        // ---- build ft[k][r]: 256 thr, j=tid&127, half rows each ----
        {
            const int j  = tid & 127;
            const int rh = tid >> 7;
            const float g = vout[j];
            const float wxj = Wx[j], bxj = bxv[j];
            const float* cb = coord + r0 + rh * 16;
            #pragma unroll
            for (int r = 0; r < 16; ++r)
                ft[j * 36 + rh * 16 + r] = __sinf(cb[r] * wxj + bxj) * g;
        }
        __syncthreads();

        // ---- GEMM: C[32 x 128] = f[32x128] @ Wo[128 x co0..co0+128) ----
        const int cq = tid & 31;           // f4-col
        const int rg = tid >> 5;           // 0..7 -> rows rg*4..rg*4+3
        float4 acc0 = make_float4(0.f, 0.f, 0.f, 0.f);
        float4 acc1 = acc0, acc2 = acc0, acc3 = acc0;

        float4 pref[4];
        #pragma unroll
        for (int i = 0; i < 4; ++i) {
            const int m = tid + 256 * i;
            pref[i] = *(const float4*)&Wo[(m >> 5) * 1024 + co0 + (m & 31) * 4];
        }
        for (int ch = 0; ch < 4; ++ch) {
            if (ch) __syncthreads();       // wlds free
            #pragma unroll
            for (int i = 0; i < 4; ++i) {
                const int m = tid + 256 * i;
                *(float4*)&wlds[(m >> 5) * 128 + (m & 31) * 4] = pref[i];
            }
            if (ch < 3) {
                const int kc = (ch + 1) * 32;
                #pragma unroll
                for (int i = 0; i < 4; ++i) {
                    const int m = tid + 256 * i;
                    pref[i] = *(const float4*)&Wo[(kc + (m >> 5)) * 1024 + co0 + (m & 31) * 4];
                }
            }
            __syncthreads();               // wlds ready
            const int kb = ch * 32;
            #pragma unroll
            for (int kk = 0; kk < 32; ++kk) {
                const float4 w  = *(const float4*)&wlds[kk * 128 + cq * 4];
                const float4 fv = *(const float4*)&ft[(kb + kk) * 36 + rg * 4];
                fma4(acc0, fv.x, w);
                fma4(acc1, fv.y, w);
                fma4(acc2, fv.z, w);
                fma4(acc3, fv.w, w);
            }
        }

        const float4 bias = *(const float4*)&bo[co0 + cq * 4];
        float* ob = outp + (r0 + rg * 4) * 1024 + co0 + cq * 4;
        float4 v;
        v.x = mult * (acc0.x + bias.x); v.y = mult * (acc0.y + bias.y);
        v.z = mult * (acc0.z + bias.z); v.w = mult * (acc0.w + bias.w);
        *(float4*)&ob[0] = v;
        v.x = mult * (acc1.x + bias.x); v.y = mult * (acc1.y + bias.y);
        v.z = mult * (acc1.z + bias.z); v.w = mult * (acc1.w + bias.w);
        *(float4*)&ob[1024] = v;
        v.x = mult * (acc2.x + bias.x); v.y = mult * (acc2.y + bias.y);
        v.z = mult * (acc2.z + bias.z); v.w = mult * (acc2.w + bias.w);
        *(float4*)&ob[2048] = v;
        v.x = mult * (acc3.x + bias.x); v.y = mult * (acc3.y + bias.y);
        v.z = mult * (acc3.z + bias.z); v.w = mult * (acc3.w + bias.w);
        *(float4*)&ob[3072] = v;
    } else {
        // ================= constants -> ws[0..31]=wc, ws[32]=K0 (R11) =======
        __shared__ float dws[128];
        if (tid < 128) { vin[tid] = p.h0[tid]; dws[tid] = p.d_W[tid]; }
        __syncthreads();
        gemv_stage(p.blk_W1, p.blk_b1, vin, vout, partf, tid);   // sacc
        if (tid < 128) {
            float w2 = 0.f;
            const float4* rp = (const float4*)&p.blk_W2[tid * 128];
            #pragma unroll
            for (int m4 = 0; m4 < 32; ++m4) {
                const float4 wv = rp[m4];
                const float4 dv = *(const float4*)&dws[m4 * 4];
                w2 += wv.x * dv.x + wv.y * dv.y + wv.z * dv.z + wv.w * dv.w;
            }
            const float sv = __sinf(vout[tid]) * w2;
            vin[tid] = sv;
            vout[tid] = (p.h0[tid] + p.blk_b2[tid]) * dws[tid] + sv * p.blk_bc[tid];
        }
        __syncthreads();
        {
            const int d  = tid >> 3;
            const int sg = (tid & 7) * 16;
            float acc = 0.f;
            #pragma unroll
            for (int i4 = 0; i4 < 4; ++i4) {
                const float4 wv = *(const float4*)&p.blk_Wc[d * 128 + sg + i4 * 4];
                const float4 sv = *(const float4*)&vin[sg + i4 * 4];
                acc += wv.x * sv.x + wv.y * sv.y + wv.z * sv.z + wv.w * sv.w;
            }
            partf[d * 8 + (tid & 7)] = acc;
        }
        __syncthreads();
        if (tid < 32) {
            float w = 0.f;
            #pragma unroll
            for (int q = 0; q < 8; ++q) w += partf[tid * 8 + q];
            p.ws[tid] = w * (1.0f / 32.0f);
        }
        if (tid < 64) vout[tid] += vout[tid + 64];
        __syncthreads();
        if (tid == 0) {
            float K = p.d_b[0];
            #pragma unroll
            for (int i = 0; i < 64; ++i) K += vout[i];
            p.ws[32] = K;
        }
    }
}

// u: R11 verbatim. 512 blocks x 256 thr.
__global__ __launch_bounds__(256, 2) void u_kernel(
    const float* __restrict__ zt, const float* __restrict__ px,
    const float* __restrict__ ws, float* __restrict__ out_u)
{
    __shared__ float4 pxs4[2080];      // [32][65]
    __shared__ float wcs[32];
    const int tid = threadIdx.x;
    const int bid = blockIdx.x;
    const int b   = bid >> 7;
    const int rem = bid & 127;
    const int t0  = (rem >> 2) * 8;
    const int x0  = (rem & 3) * 32;

    if (tid < 32) wcs[tid] = ws[tid];
    const float K0 = ws[32];
    const int tx = tid & 31;
    const int ty = tid >> 5;           // 0..7
    const float* ztb = zt + (b * 256 + t0) * 1024;
    const float* pxb = px + (b * 128 + x0) * 1024;
    __syncthreads();

    float acc = 0.f;
    for (int chunk = 0; chunk < 4; ++chunk) {
        const int kc = chunk * 256;
        if (chunk) __syncthreads();
        #pragma unroll
        for (int i = 0; i < 8; ++i) {
            const int m  = tid + 256 * i;
            const int xx = m >> 6;
            const int jf = m & 63;
            float4 v = *(const float4*)&pxb[xx * 1024 + kc + jf * 4];
            const float sc = wcs[(kc >> 5) + (jf >> 3)];
            v.x *= sc; v.y *= sc; v.z *= sc; v.w *= sc;
            pxs4[xx * 65 + jf] = v;
        }
        __syncthreads();

        float4 za[8];
        #pragma unroll
        for (int j2 = 0; j2 < 8; ++j2)
            za[j2] = *(const float4*)&ztb[ty * 1024 + kc + j2 * 4];
        #pragma unroll
        for (int jj = 0; jj < 8; ++jj) {
            float4 nz[8];
            if (jj < 7) {
                const int koff = kc + (jj + 1) * 32;
                #pragma unroll
                for (int j2 = 0; j2 < 8; ++j2)
                    nz[j2] = *(const float4*)&ztb[ty * 1024 + koff + j2 * 4];
            }
            #pragma unroll
            for (int j2 = 0; j2 < 8; ++j2) {
                const float4 q = pxs4[tx * 65 + jj * 8 + j2];
                acc += za[j2].x * q.x + za[j2].y * q.y
                     + za[j2].z * q.z + za[j2].w * q.w;
            }
            if (jj < 7) {
                #pragma unroll
                for (int j2 = 0; j2 < 8; ++j2) za[j2] = nz[j2];
            }
        }
    }
    out_u[(b * 256 + t0 + ty) * 128 + x0 + tx] = K0 + acc;
}

extern "C" void kernel_launch(void* const* d_in, const int* in_sizes, int n_in,
                              void* d_out, int out_size, void* d_ws, size_t ws_size,
                              hipStream_t stream) {
    float* out = (float*)d_out;
    float* ws  = (float*)d_ws;

    P prm;
    prm.x       = (const float*)d_in[0];
    prm.t       = (const float*)d_in[1];
    prm.param   = (const float*)d_in[2];
    prm.p2e_W1  = (const float*)d_in[3];
    prm.p2e_b1  = (const float*)d_in[4];
    prm.p2e_W2  = (const float*)d_in[5];
    prm.p2e_b2  = (const float*)d_in[6];
    prm.e2ex_W  = (const float*)d_in[7];
    prm.e2ex_b  = (const float*)d_in[8];
    prm.e2et_W  = (const float*)d_in[9];
    prm.e2et_b  = (const float*)d_in[10];
    prm.px_Wx   = (const float*)d_in[11];
    prm.px_bx   = (const float*)d_in[12];
    prm.px_We   = (const float*)d_in[13];
    prm.px_be   = (const float*)d_in[14];
    prm.px_Wo   = (const float*)d_in[15];
    prm.px_bo   = (const float*)d_in[16];
    prm.px_mult = (const float*)d_in[17];
    prm.zt_Wx   = (const float*)d_in[18];
    prm.zt_bx   = (const float*)d_in[19];
    prm.zt_We   = (const float*)d_in[20];
    prm.zt_be   = (const float*)d_in[21];
    prm.zt_Wo   = (const float*)d_in[22];
    prm.zt_bo   = (const float*)d_in[23];
    prm.zt_mult = (const float*)d_in[24];
    prm.h0      = (const float*)d_in[25];
    prm.blk_W1  = (const float*)d_in[26];
    prm.blk_b1  = (const float*)d_in[27];
    prm.blk_Wc  = (const float*)d_in[28];
    prm.blk_bc  = (const float*)d_in[29];
    prm.blk_W2  = (const float*)d_in[30];
    prm.blk_b2  = (const float*)d_in[31];
    prm.d_W     = (const float*)d_in[32];
    prm.d_b     = (const float*)d_in[33];
    prm.out_u   = out;                        // 131072
    prm.out_zt  = out + 131072;               // 1048576
    prm.out_px  = out + 131072 + 1048576;     // 524288
    prm.ws      = ws;

    feat_kernel<<<385, 256, 0, stream>>>(prm);
    u_kernel<<<512, 256, 0, stream>>>(prm.out_zt, prm.out_px, ws, out);
}

// Round 16
// 46.696 us; speedup vs baseline: 1.2643x; 1.0000x over previous
//
#include <hip/hip_runtime.h>
#include <math.h>

// B=4, X=128, T=256, HIDDEN=128, EMB=128, DH=32, LATENT=32, K=1024
// Outputs concat: u (131072), zt (1048576), px (524288)
// u[b,t,x] = K0 + sum_k zt[b,t,k]*px[b,x,k]*wc[k>>5]   (wc = wcd/32)
//
// R15 = R11 with feat GEMM re-tiled: 32 rows x 128 cols per block, weights
// staged through LDS once (24 MB total vs R11's 196 MB), ft transposed in LDS.
// u_kernel and constants block are R11 verbatim.

struct P {
    const float *x, *t, *param;
    const float *p2e_W1, *p2e_b1, *p2e_W2, *p2e_b2;
    const float *e2ex_W, *e2ex_b, *e2et_W, *e2et_b;
    const float *px_Wx, *px_bx, *px_We, *px_be, *px_Wo, *px_bo, *px_mult;
    const float *zt_Wx, *zt_bx, *zt_We, *zt_be, *zt_Wo, *zt_bo, *zt_mult;
    const float *h0, *blk_W1, *blk_b1, *blk_Wc, *blk_bc, *blk_W2, *blk_b2;
    const float *d_W, *d_b;
    float *out_u, *out_zt, *out_px, *ws;
};

__device__ __forceinline__ void fma4(float4& a, float s, const float4& v) {
    a.x += s * v.x; a.y += s * v.y; a.z += s * v.z; a.w += s * v.w;
}

// out[j] = bias[j] + sum_k vin[k] * W[k*128+j]; 256 threads. (R11 validated)
__device__ __forceinline__ void gemv_stage(
    const float* __restrict__ W, const float* __restrict__ bias,
    const float* vin, float* vout, float* partf, int tid)
{
    const int j4 = tid & 31;
    const int sl = tid >> 5;
    float4 a4 = make_float4(0.f, 0.f, 0.f, 0.f);
    const float* Wp = W + sl * 16 * 128 + j4 * 4;
    #pragma unroll
    for (int k = 0; k < 16; ++k)
        fma4(a4, vin[sl * 16 + k], *(const float4*)&Wp[k * 128]);
    *(float4*)&partf[sl * 128 + j4 * 4] = a4;
    __syncthreads();
    if (tid < 128) {
        float v = bias[tid];
        #pragma unroll
        for (int q = 0; q < 8; ++q) v += partf[q * 128 + tid];
        vout[tid] = v;
    }
    __syncthreads();
}

__global__ __launch_bounds__(256, 2) void feat_kernel(P p) {
    __shared__ float vin[128], vout[128];
    __shared__ float partf[1024];
    __shared__ float ft[128 * 36];      // f^T [k][row], row-pad 36 (f4-aligned)
    __shared__ float wlds[32 * 128];    // weight chunk [k][col]
    const int tid = threadIdx.x;
    const int bid = blockIdx.x;

    if (bid < 384) {
        // decode: px blocks 0-127 (4b x 4rt x 8cq), zt blocks 128-383 (4b x 8rt x 8cq)
        const bool is_zt = bid >= 128;
        int b, rt, cq8;
        if (!is_zt) { const int un = bid;       b = un >> 5; rt = (un >> 3) & 3; cq8 = un & 7; }
        else        { const int un = bid - 128; b = un >> 6; rt = (un >> 3) & 7; cq8 = un & 7; }
        const int r0  = b * (is_zt ? 256 : 128) + rt * 32;   // global row
        const int co0 = cq8 * 128;

        const float* Wh = is_zt ? p.e2et_W : p.e2ex_W;
        const float* bh = is_zt ? p.e2et_b : p.e2ex_b;
        const float* We = is_zt ? p.zt_We : p.px_We;
        const float* be = is_zt ? p.zt_be : p.px_be;
        const float* Wx = is_zt ? p.zt_Wx : p.px_Wx;
        const float* bxv = is_zt ? p.zt_bx : p.px_bx;
        const float* Wo = is_zt ? p.zt_Wo : p.px_Wo;
        const float* bo = is_zt ? p.zt_bo : p.px_bo;
        const float* coord = is_zt ? p.t : p.x;
        const float mult = is_zt ? p.zt_mult[0] : p.px_mult[0];
        float* outp = is_zt ? p.out_zt : p.out_px;

        // ---- g-chain (R11 validated) ----
        if (tid < 128) {
            float a = p.p2e_b1[tid];
            #pragma unroll
            for (int q = 0; q < 16; ++q)
                a += p.param[b * 16 + q] * p.p2e_W1[q * 128 + tid];
            vin[tid] = __sinf(a);
        }
        __syncthreads();
        gemv_stage(p.p2e_W2, p.p2e_b2, vin, vout, partf, tid);   // e
        gemv_stage(Wh, bh, vout, vin, partf, tid);               // ex/et
        gemv_stage(We, be, vin, vout, partf, tid);               // g in vout

        // ---- build ft[k][r]: 256 thr, j=tid&127, half rows each ----
        {
            const int j  = tid & 127;
            const int rh = tid >> 7;
            const float g = vout[j];
            const float wxj = Wx[j], bxj = bxv[j];
            const float* cb = coord + r0 + rh * 16;
            #pragma unroll
            for (int r = 0; r < 16; ++r)
                ft[j * 36 + rh * 16 + r] = __sinf(cb[r] * wxj + bxj) * g;
        }
        __syncthreads();

        // ---- GEMM: C[32 x 128] = f[32x128] @ Wo[128 x co0..co0+128) ----
        const int cq = tid & 31;           // f4-col
        const int rg = tid >> 5;           // 0..7 -> rows rg*4..rg*4+3
        float4 acc0 = make_float4(0.f, 0.f, 0.f, 0.f);
        float4 acc1 = acc0, acc2 = acc0, acc3 = acc0;

        float4 pref[4];
        #pragma unroll
        for (int i = 0; i < 4; ++i) {
            const int m = tid + 256 * i;
            pref[i] = *(const float4*)&Wo[(m >> 5) * 1024 + co0 + (m & 31) * 4];
        }
        for (int ch = 0; ch < 4; ++ch) {
            if (ch) __syncthreads();       // wlds free
            #pragma unroll
            for (int i = 0; i < 4; ++i) {
                const int m = tid + 256 * i;
                *(float4*)&wlds[(m >> 5) * 128 + (m & 31) * 4] = pref[i];
            }
            if (ch < 3) {
                const int kc = (ch + 1) * 32;
                #pragma unroll
                for (int i = 0; i < 4; ++i) {
                    const int m = tid + 256 * i;
                    pref[i] = *(const float4*)&Wo[(kc + (m >> 5)) * 1024 + co0 + (m & 31) * 4];
                }
            }
            __syncthreads();               // wlds ready
            const int kb = ch * 32;
            #pragma unroll
            for (int kk = 0; kk < 32; ++kk) {
                const float4 w  = *(const float4*)&wlds[kk * 128 + cq * 4];
                const float4 fv = *(const float4*)&ft[(kb + kk) * 36 + rg * 4];
                fma4(acc0, fv.x, w);
                fma4(acc1, fv.y, w);
                fma4(acc2, fv.z, w);
                fma4(acc3, fv.w, w);
            }
        }

        const float4 bias = *(const float4*)&bo[co0 + cq * 4];
        float* ob = outp + (r0 + rg * 4) * 1024 + co0 + cq * 4;
        float4 v;
        v.x = mult * (acc0.x + bias.x); v.y = mult * (acc0.y + bias.y);
        v.z = mult * (acc0.z + bias.z); v.w = mult * (acc0.w + bias.w);
        *(float4*)&ob[0] = v;
        v.x = mult * (acc1.x + bias.x); v.y = mult * (acc1.y + bias.y);
        v.z = mult * (acc1.z + bias.z); v.w = mult * (acc1.w + bias.w);
        *(float4*)&ob[1024] = v;
        v.x = mult * (acc2.x + bias.x); v.y = mult * (acc2.y + bias.y);
        v.z = mult * (acc2.z + bias.z); v.w = mult * (acc2.w + bias.w);
        *(float4*)&ob[2048] = v;
        v.x = mult * (acc3.x + bias.x); v.y = mult * (acc3.y + bias.y);
        v.z = mult * (acc3.z + bias.z); v.w = mult * (acc3.w + bias.w);
        *(float4*)&ob[3072] = v;
    } else {
        // ================= constants -> ws[0..31]=wc, ws[32]=K0 (R11) =======
        __shared__ float dws[128];
        if (tid < 128) { vin[tid] = p.h0[tid]; dws[tid] = p.d_W[tid]; }
        __syncthreads();
        gemv_stage(p.blk_W1, p.blk_b1, vin, vout, partf, tid);   // sacc
        if (tid < 128) {
            float w2 = 0.f;
            const float4* rp = (const float4*)&p.blk_W2[tid * 128];
            #pragma unroll
            for (int m4 = 0; m4 < 32; ++m4) {
                const float4 wv = rp[m4];
                const float4 dv = *(const float4*)&dws[m4 * 4];
                w2 += wv.x * dv.x + wv.y * dv.y + wv.z * dv.z + wv.w * dv.w;
            }
            const float sv = __sinf(vout[tid]) * w2;
            vin[tid] = sv;
            vout[tid] = (p.h0[tid] + p.blk_b2[tid]) * dws[tid] + sv * p.blk_bc[tid];
        }
        __syncthreads();
        {
            const int d  = tid >> 3;
            const int sg = (tid & 7) * 16;
            float acc = 0.f;
            #pragma unroll
            for (int i4 = 0; i4 < 4; ++i4) {
                const float4 wv = *(const float4*)&p.blk_Wc[d * 128 + sg + i4 * 4];
                const float4 sv = *(const float4*)&vin[sg + i4 * 4];
                acc += wv.x * sv.x + wv.y * sv.y + wv.z * sv.z + wv.w * sv.w;
            }
            partf[d * 8 + (tid & 7)] = acc;
        }
        __syncthreads();
        if (tid < 32) {
            float w = 0.f;
            #pragma unroll
            for (int q = 0; q < 8; ++q) w += partf[tid * 8 + q];
            p.ws[tid] = w * (1.0f / 32.0f);
        }
        if (tid < 64) vout[tid] += vout[tid + 64];
        __syncthreads();
        if (tid == 0) {
            float K = p.d_b[0];
            #pragma unroll
            for (int i = 0; i < 64; ++i) K += vout[i];
            p.ws[32] = K;
        }
    }
}

// u: R11 verbatim. 512 blocks x 256 thr.
__global__ __launch_bounds__(256, 2) void u_kernel(
    const float* __restrict__ zt, const float* __restrict__ px,
    const float* __restrict__ ws, float* __restrict__ out_u)
{
    __shared__ float4 pxs4[2080];      // [32][65]
    __shared__ float wcs[32];
    const int tid = threadIdx.x;
    const int bid = blockIdx.x;
    const int b   = bid >> 7;
    const int rem = bid & 127;
    const int t0  = (rem >> 2) * 8;
    const int x0  = (rem & 3) * 32;

    if (tid < 32) wcs[tid] = ws[tid];
    const float K0 = ws[32];
    const int tx = tid & 31;
    const int ty = tid >> 5;           // 0..7
    const float* ztb = zt + (b * 256 + t0) * 1024;
    const float* pxb = px + (b * 128 + x0) * 1024;
    __syncthreads();

    float acc = 0.f;
    for (int chunk = 0; chunk < 4; ++chunk) {
        const int kc = chunk * 256;
        if (chunk) __syncthreads();
        #pragma unroll
        for (int i = 0; i < 8; ++i) {
            const int m  = tid + 256 * i;
            const int xx = m >> 6;
            const int jf = m & 63;
            float4 v = *(const float4*)&pxb[xx * 1024 + kc + jf * 4];
            const float sc = wcs[(kc >> 5) + (jf >> 3)];
            v.x *= sc; v.y *= sc; v.z *= sc; v.w *= sc;
            pxs4[xx * 65 + jf] = v;
        }
        __syncthreads();

        float4 za[8];
        #pragma unroll
        for (int j2 = 0; j2 < 8; ++j2)
            za[j2] = *(const float4*)&ztb[ty * 1024 + kc + j2 * 4];
        #pragma unroll
        for (int jj = 0; jj < 8; ++jj) {
            float4 nz[8];
            if (jj < 7) {
                const int koff = kc + (jj + 1) * 32;
                #pragma unroll
                for (int j2 = 0; j2 < 8; ++j2)
                    nz[j2] = *(const float4*)&ztb[ty * 1024 + koff + j2 * 4];
            }
            #pragma unroll
            for (int j2 = 0; j2 < 8; ++j2) {
                const float4 q = pxs4[tx * 65 + jj * 8 + j2];
                acc += za[j2].x * q.x + za[j2].y * q.y
                     + za[j2].z * q.z + za[j2].w * q.w;
            }
            if (jj < 7) {
                #pragma unroll
                for (int j2 = 0; j2 < 8; ++j2) za[j2] = nz[j2];
            }
        }
    }
    out_u[(b * 256 + t0 + ty) * 128 + x0 + tx] = K0 + acc;
}

extern "C" void kernel_launch(void* const* d_in, const int* in_sizes, int n_in,
                              void* d_out, int out_size, void* d_ws, size_t ws_size,
                              hipStream_t stream) {
    float* out = (float*)d_out;
    float* ws  = (float*)d_ws;

    P prm;
    prm.x       = (const float*)d_in[0];
    prm.t       = (const float*)d_in[1];
    prm.param   = (const float*)d_in[2];
    prm.p2e_W1  = (const float*)d_in[3];
    prm.p2e_b1  = (const float*)d_in[4];
    prm.p2e_W2  = (const float*)d_in[5];
    prm.p2e_b2  = (const float*)d_in[6];
    prm.e2ex_W  = (const float*)d_in[7];
    prm.e2ex_b  = (const float*)d_in[8];
    prm.e2et_W  = (const float*)d_in[9];
    prm.e2et_b  = (const float*)d_in[10];
    prm.px_Wx   = (const float*)d_in[11];
    prm.px_bx   = (const float*)d_in[12];
    prm.px_We   = (const float*)d_in[13];
    prm.px_be   = (const float*)d_in[14];
    prm.px_Wo   = (const float*)d_in[15];
    prm.px_bo   = (const float*)d_in[16];
    prm.px_mult = (const float*)d_in[17];
    prm.zt_Wx   = (const float*)d_in[18];
    prm.zt_bx   = (const float*)d_in[19];
    prm.zt_We   = (const float*)d_in[20];
    prm.zt_be   = (const float*)d_in[21];
    prm.zt_Wo   = (const float*)d_in[22];
    prm.zt_bo   = (const float*)d_in[23];
    prm.zt_mult = (const float*)d_in[24];
    prm.h0      = (const float*)d_in[25];
    prm.blk_W1  = (const float*)d_in[26];
    prm.blk_b1  = (const float*)d_in[27];
    prm.blk_Wc  = (const float*)d_in[28];
    prm.blk_bc  = (const float*)d_in[29];
    prm.blk_W2  = (const float*)d_in[30];
    prm.blk_b2  = (const float*)d_in[31];
    prm.d_W     = (const float*)d_in[32];
    prm.d_b     = (const float*)d_in[33];
    prm.out_u   = out;                        // 131072
    prm.out_zt  = out + 131072;               // 1048576
    prm.out_px  = out + 131072 + 1048576;     // 524288
    prm.ws      = ws;

    feat_kernel<<<385, 256, 0, stream>>>(prm);
    u_kernel<<<512, 256, 0, stream>>>(prm.out_zt, prm.out_px, ws, out);
}

// Round 17
// 43.818 us; speedup vs baseline: 1.3473x; 1.0657x over previous
//
#include <hip/hip_runtime.h>
#include <math.h>

// B=4, X=128, T=256, HIDDEN=128, EMB=128, DH=32, LATENT=32, K=1024
// Outputs concat: u (131072), zt (1048576), px (524288)
// u[b,t,x] = K0 + sum_k zt[b,t,k]*px[b,x,k]*wc[k>>5]   (wc = wcd/32)
//
// R17 = R11 feat verbatim (best known: 42.5us total) + u with 2 outputs per
// thread (halves per-output LDS ds_read_b128 pressure; R7-validated pattern).

struct P {
    const float *x, *t, *param;
    const float *p2e_W1, *p2e_b1, *p2e_W2, *p2e_b2;
    const float *e2ex_W, *e2ex_b, *e2et_W, *e2et_b;
    const float *px_Wx, *px_bx, *px_We, *px_be, *px_Wo, *px_bo, *px_mult;
    const float *zt_Wx, *zt_bx, *zt_We, *zt_be, *zt_Wo, *zt_bo, *zt_mult;
    const float *h0, *blk_W1, *blk_b1, *blk_Wc, *blk_bc, *blk_W2, *blk_b2;
    const float *d_W, *d_b;
    float *out_u, *out_zt, *out_px, *ws;
};

__device__ __forceinline__ void fma4(float4& a, float s, const float4& v) {
    a.x += s * v.x; a.y += s * v.y; a.z += s * v.z; a.w += s * v.w;
}

// out[j] = bias[j] + sum_k vin[k] * W[k*128+j]; 256 threads. (R11 validated)
__device__ __forceinline__ void gemv_stage(
    const float* __restrict__ W, const float* __restrict__ bias,
    const float* vin, float* vout, float* partf, int tid)
{
    const int j4 = tid & 31;
    const int sl = tid >> 5;
    float4 a4 = make_float4(0.f, 0.f, 0.f, 0.f);
    const float* Wp = W + sl * 16 * 128 + j4 * 4;
    #pragma unroll
    for (int k = 0; k < 16; ++k)
        fma4(a4, vin[sl * 16 + k], *(const float4*)&Wp[k * 128]);
    *(float4*)&partf[sl * 128 + j4 * 4] = a4;
    __syncthreads();
    if (tid < 128) {
        float v = bias[tid];
        #pragma unroll
        for (int q = 0; q < 8; ++q) v += partf[q * 128 + tid];
        vout[tid] = v;
    }
    __syncthreads();
}

__global__ __launch_bounds__(256, 2) void feat_kernel(P p) {
    __shared__ float vin[128], vout[128];
    __shared__ float partf[1024];
    __shared__ float f[8 * 128];
    const int tid = threadIdx.x;
    const int bid = blockIdx.x;

    if (bid < 384) {
        const bool is_zt = bid >= 128;
        const int un = is_zt ? bid - 128 : bid;
        const int rt = un >> 1, cs = un & 1;
        const int r0 = rt * 8;
        const int b = is_zt ? (r0 >> 8) : (r0 >> 7);

        const float* Wh = is_zt ? p.e2et_W : p.e2ex_W;
        const float* bh = is_zt ? p.e2et_b : p.e2ex_b;
        const float* We = is_zt ? p.zt_We : p.px_We;
        const float* be = is_zt ? p.zt_be : p.px_be;
        const float* Wx = is_zt ? p.zt_Wx : p.px_Wx;
        const float* bxv = is_zt ? p.zt_bx : p.px_bx;
        const float* Wo = is_zt ? p.zt_Wo : p.px_Wo;
        const float* bo = is_zt ? p.zt_bo : p.px_bo;
        const float* coord = is_zt ? p.t : p.x;
        const float mult = is_zt ? p.zt_mult[0] : p.px_mult[0];
        float* outp = is_zt ? p.out_zt : p.out_px;

        if (tid < 128) {
            float a = p.p2e_b1[tid];
            #pragma unroll
            for (int q = 0; q < 16; ++q)
                a += p.param[b * 16 + q] * p.p2e_W1[q * 128 + tid];
            vin[tid] = __sinf(a);
        }
        __syncthreads();
        gemv_stage(p.p2e_W2, p.p2e_b2, vin, vout, partf, tid);   // e
        gemv_stage(Wh, bh, vout, vin, partf, tid);               // ex/et
        gemv_stage(We, be, vin, vout, partf, tid);               // g
        if (tid < 128) {
            const float g = vout[tid];
            const float wxj = Wx[tid], bxj = bxv[tid];
            #pragma unroll
            for (int rr = 0; rr < 8; ++rr)
                f[rr * 128 + tid] = __sinf(coord[r0 + rr] * wxj + bxj) * g;
        }
        __syncthreads();

        const int c = tid & 127;
        const int h = tid >> 7;
        const int c0 = cs * 512 + c * 4;
        const float* wp = Wo + c0;
        const float* fr = f + h * 4 * 128;

        float4 acc[4];
        #pragma unroll
        for (int rr = 0; rr < 4; ++rr) acc[rr] = make_float4(0.f, 0.f, 0.f, 0.f);

        float4 wA[8], wB[8];
        #pragma unroll
        for (int i = 0; i < 8; ++i) wA[i] = *(const float4*)&wp[i * 1024];

        #pragma unroll
        for (int g2 = 0; g2 < 8; ++g2) {
            #pragma unroll
            for (int i = 0; i < 8; ++i)
                wB[i] = *(const float4*)&wp[((2 * g2 + 1) * 8 + i) * 1024];
            {
                const int k0 = 16 * g2;
                #pragma unroll
                for (int rr = 0; rr < 4; ++rr) {
                    const float4 f0 = *(const float4*)&fr[rr * 128 + k0];
                    const float4 f1 = *(const float4*)&fr[rr * 128 + k0 + 4];
                    fma4(acc[rr], f0.x, wA[0]); fma4(acc[rr], f0.y, wA[1]);
                    fma4(acc[rr], f0.z, wA[2]); fma4(acc[rr], f0.w, wA[3]);
                    fma4(acc[rr], f1.x, wA[4]); fma4(acc[rr], f1.y, wA[5]);
                    fma4(acc[rr], f1.z, wA[6]); fma4(acc[rr], f1.w, wA[7]);
                }
            }
            if (g2 < 7) {
                #pragma unroll
                for (int i = 0; i < 8; ++i)
                    wA[i] = *(const float4*)&wp[((2 * g2 + 2) * 8 + i) * 1024];
            }
            {
                const int k0 = 16 * g2 + 8;
                #pragma unroll
                for (int rr = 0; rr < 4; ++rr) {
                    const float4 f0 = *(const float4*)&fr[rr * 128 + k0];
                    const float4 f1 = *(const float4*)&fr[rr * 128 + k0 + 4];
                    fma4(acc[rr], f0.x, wB[0]); fma4(acc[rr], f0.y, wB[1]);
                    fma4(acc[rr], f0.z, wB[2]); fma4(acc[rr], f0.w, wB[3]);
                    fma4(acc[rr], f1.x, wB[4]); fma4(acc[rr], f1.y, wB[5]);
                    fma4(acc[rr], f1.z, wB[6]); fma4(acc[rr], f1.w, wB[7]);
                }
            }
        }

        const float4 bias = *(const float4*)&bo[c0];
        #pragma unroll
        for (int rr = 0; rr < 4; ++rr) {
            float4 v;
            v.x = mult * (acc[rr].x + bias.x);
            v.y = mult * (acc[rr].y + bias.y);
            v.z = mult * (acc[rr].z + bias.z);
            v.w = mult * (acc[rr].w + bias.w);
            *(float4*)&outp[(r0 + h * 4 + rr) * 1024 + c0] = v;
        }
    } else {
        // ================= constants -> ws[0..31]=wc, ws[32]=K0 =============
        __shared__ float dws[128];
        if (tid < 128) { vin[tid] = p.h0[tid]; dws[tid] = p.d_W[tid]; }
        __syncthreads();
        gemv_stage(p.blk_W1, p.blk_b1, vin, vout, partf, tid);   // sacc
        if (tid < 128) {
            float w2 = 0.f;
            const float4* rp = (const float4*)&p.blk_W2[tid * 128];
            #pragma unroll
            for (int m4 = 0; m4 < 32; ++m4) {
                const float4 wv = rp[m4];
                const float4 dv = *(const float4*)&dws[m4 * 4];
                w2 += wv.x * dv.x + wv.y * dv.y + wv.z * dv.z + wv.w * dv.w;
            }
            const float sv = __sinf(vout[tid]) * w2;
            vin[tid] = sv;
            vout[tid] = (p.h0[tid] + p.blk_b2[tid]) * dws[tid] + sv * p.blk_bc[tid];
        }
        __syncthreads();
        {
            const int d  = tid >> 3;
            const int sg = (tid & 7) * 16;
            float acc = 0.f;
            #pragma unroll
            for (int i4 = 0; i4 < 4; ++i4) {
                const float4 wv = *(const float4*)&p.blk_Wc[d * 128 + sg + i4 * 4];
                const float4 sv = *(const float4*)&vin[sg + i4 * 4];
                acc += wv.x * sv.x + wv.y * sv.y + wv.z * sv.z + wv.w * sv.w;
            }
            partf[d * 8 + (tid & 7)] = acc;
        }
        __syncthreads();
        if (tid < 32) {
            float w = 0.f;
            #pragma unroll
            for (int q = 0; q < 8; ++q) w += partf[tid * 8 + q];
            p.ws[tid] = w * (1.0f / 32.0f);
        }
        if (tid < 64) vout[tid] += vout[tid + 64];
        __syncthreads();
        if (tid == 0) {
            float K = p.d_b[0];
            #pragma unroll
            for (int i = 0; i < 64; ++i) K += vout[i];
            p.ws[32] = K;
        }
    }
}

// u: 512 blocks x 128 thr (R7-validated pattern, ws offsets adapted).
// Thread (tx=tid&31, ty=tid>>5 in 0..3): outputs rows t0+ty, t0+ty+4.
// Each pxs4 LDS read feeds 2 fma4 (2:1) -> half the LDS-pipe pressure of R11.
__global__ __launch_bounds__(128) void u_kernel(
    const float* __restrict__ zt, const float* __restrict__ px,
    const float* __restrict__ ws, float* __restrict__ out_u)
{
    __shared__ float4 pxs4[32][65];
    __shared__ float wcs[32];
    const int tid = threadIdx.x;
    const int blk = blockIdx.x;
    const int b   = blk >> 7;
    const int rem = blk & 127;
    const int t0  = (rem >> 2) * 8;
    const int x0  = (rem & 3) * 32;

    if (tid < 32) wcs[tid] = ws[tid];
    const float K0 = ws[32];

    const int tx = tid & 31;
    const int ty = tid >> 5;          // 0..3

    const float* ztb = zt + (b * 256 + t0) * 1024;
    const float* pxb = px + (b * 128 + x0) * 1024;
    __syncthreads();                  // wcs visible

    float acc0 = 0.f, acc1 = 0.f;

    for (int chunk = 0; chunk < 4; ++chunk) {
        const int kc = chunk * 256;
        if (chunk) __syncthreads();
        // stage px chunk: 32 x-rows x 64 f4, scaled; 16 f4 per thread
        #pragma unroll
        for (int i = 0; i < 16; ++i) {
            const int m  = tid + 128 * i;
            const int xx = m >> 6;
            const int jf = m & 63;
            float4 v = *(const float4*)&pxb[xx * 1024 + kc + jf * 4];
            const float sc = wcs[(kc >> 5) + (jf >> 3)];
            v.x *= sc; v.y *= sc; v.z *= sc; v.w *= sc;
            pxs4[xx][jf] = v;
        }
        __syncthreads();

        float4 za[8], zb[8];
        #pragma unroll
        for (int j2 = 0; j2 < 8; ++j2) {
            za[j2] = *(const float4*)&ztb[ty * 1024 + kc + j2 * 4];
            zb[j2] = *(const float4*)&ztb[(ty + 4) * 1024 + kc + j2 * 4];
        }
        #pragma unroll
        for (int jj = 0; jj < 8; ++jj) {
            float4 nza[8], nzb[8];
            if (jj < 7) {
                const int koff = kc + (jj + 1) * 32;
                #pragma unroll
                for (int j2 = 0; j2 < 8; ++j2) {
                    nza[j2] = *(const float4*)&ztb[ty * 1024 + koff + j2 * 4];
                    nzb[j2] = *(const float4*)&ztb[(ty + 4) * 1024 + koff + j2 * 4];
                }
            }
            #pragma unroll
            for (int j2 = 0; j2 < 8; ++j2) {
                const float4 q = pxs4[tx][jj * 8 + j2];
                acc0 += za[j2].x * q.x + za[j2].y * q.y
                      + za[j2].z * q.z + za[j2].w * q.w;
                acc1 += zb[j2].x * q.x + zb[j2].y * q.y
                      + zb[j2].z * q.z + zb[j2].w * q.w;
            }
            if (jj < 7) {
                #pragma unroll
                for (int j2 = 0; j2 < 8; ++j2) { za[j2] = nza[j2]; zb[j2] = nzb[j2]; }
            }
        }
    }

    out_u[(b * 256 + t0 + ty)     * 128 + x0 + tx] = K0 + acc0;
    out_u[(b * 256 + t0 + ty + 4) * 128 + x0 + tx] = K0 + acc1;
}

extern "C" void kernel_launch(void* const* d_in, const int* in_sizes, int n_in,
                              void* d_out, int out_size, void* d_ws, size_t ws_size,
                              hipStream_t stream) {
    float* out = (float*)d_out;
    float* ws  = (float*)d_ws;

    P prm;
    prm.x       = (const float*)d_in[0];
    prm.t       = (const float*)d_in[1];
    prm.param   = (const float*)d_in[2];
    prm.p2e_W1  = (const float*)d_in[3];
    prm.p2e_b1  = (const float*)d_in[4];
    prm.p2e_W2  = (const float*)d_in[5];
    prm.p2e_b2  = (const float*)d_in[6];
    prm.e2ex_W  = (const float*)d_in[7];
    prm.e2ex_b  = (const float*)d_in[8];
    prm.e2et_W  = (const float*)d_in[9];
    prm.e2et_b  = (const float*)d_in[10];
    prm.px_Wx   = (const float*)d_in[11];
    prm.px_bx   = (const float*)d_in[12];
    prm.px_We   = (const float*)d_in[13];
    prm.px_be   = (const float*)d_in[14];
    prm.px_Wo   = (const float*)d_in[15];
    prm.px_bo   = (const float*)d_in[16];
    prm.px_mult = (const float*)d_in[17];
    prm.zt_Wx   = (const float*)d_in[18];
    prm.zt_bx   = (const float*)d_in[19];
    prm.zt_We   = (const float*)d_in[20];
    prm.zt_be   = (const float*)d_in[21];
    prm.zt_Wo   = (const float*)d_in[22];
    prm.zt_bo   = (const float*)d_in[23];
    prm.zt_mult = (const float*)d_in[24];
    prm.h0      = (const float*)d_in[25];
    prm.blk_W1  = (const float*)d_in[26];
    prm.blk_b1  = (const float*)d_in[27];
    prm.blk_Wc  = (const float*)d_in[28];
    prm.blk_bc  = (const float*)d_in[29];
    prm.blk_W2  = (const float*)d_in[30];
    prm.blk_b2  = (const float*)d_in[31];
    prm.d_W     = (const float*)d_in[32];
    prm.d_b     = (const float*)d_in[33];
    prm.out_u   = out;                        // 131072
    prm.out_zt  = out + 131072;               // 1048576
    prm.out_px  = out + 131072 + 1048576;     // 524288
    prm.ws      = ws;

    feat_kernel<<<385, 256, 0, stream>>>(prm);
    u_kernel<<<512, 128, 0, stream>>>(prm.out_zt, prm.out_px, ws, out);
}